// Round 6
// baseline (322.553 us; speedup 1.0000x reference)
//
#include <hip/hip_runtime.h>

// Voxelizer, round 6: gather/tile rewrite to eliminate scattered global atomics.
// Evidence: R3 (1 thr/pt, 41us), R4 (5x threads, ~37us), R5 (4.6x fewer sites,
// ~36us) -- splat time is invariant to parallelism and VALU work; the shared
// serialized resource is the ~0.7M scattered device-scope f32 atomicAdds
// (~20 G/s implied). This version: each block owns a 32x16x8 voxel tile in LDS,
// scans a prepacked base-voxel array (4 B/pt), queues intersecting points,
// splats into LDS via ds_add_f32, then writes the tile with coalesced
// full-cache-line float4 stores. Zero global atomics; no memset needed
// (tiles cover the volume exactly, each voxel stored once).

#define VOX 128
#define W0 8    // tile extent dim0 (z, slowest)
#define W1 16   // tile extent dim1
#define W2 32   // tile extent dim2 (x, fastest; 32 f32 = one 128B line)
#define CAP 2048  // queue capacity; expected ~412 pts/tile (Poisson), 5x headroom

__global__ __launch_bounds__(256) void prep_points(
    const float* __restrict__ positions,  // (N,3)
    const float* __restrict__ scales,     // (N,3)
    const float* __restrict__ rotations,  // (N,4) w,x,y,z
    const float* __restrict__ density,    // (N,)
    unsigned int* __restrict__ packed,    // (N,) base voxel, 3x8 bits
    float4* __restrict__ rec,             // (N,4) {c,dens},{mrow0,0},{mrow1,0},{mrow2,0}
    int n)
{
    const int i = blockIdx.x * blockDim.x + threadIdx.x;
    if (i >= n) return;

    const float c0 = (positions[3 * i + 0] + 1.0f) * 64.0f - 0.5f;
    const float c1 = (positions[3 * i + 1] + 1.0f) * 64.0f - 0.5f;
    const float c2 = (positions[3 * i + 2] + 1.0f) * 64.0f - 0.5f;

    // base voxel via round-half-even (matches jnp.round); range [0,128]
    const int b0 = (int)rintf(c0);
    const int b1 = (int)rintf(c1);
    const int b2 = (int)rintf(c2);
    packed[i] = (unsigned)b0 | ((unsigned)b1 << 8) | ((unsigned)b2 << 16);

    float qw = rotations[4 * i + 0];
    float qx = rotations[4 * i + 1];
    float qy = rotations[4 * i + 2];
    float qz = rotations[4 * i + 3];
    const float qn = rsqrtf(qw * qw + qx * qx + qy * qy + qz * qz);
    qw *= qn; qx *= qn; qy *= qn; qz *= qn;

    const float r00 = 1.0f - 2.0f * (qy * qy + qz * qz);
    const float r01 = 2.0f * (qx * qy - qw * qz);
    const float r02 = 2.0f * (qx * qz + qw * qy);
    const float r10 = 2.0f * (qx * qy + qw * qz);
    const float r11 = 1.0f - 2.0f * (qx * qx + qz * qz);
    const float r12 = 2.0f * (qy * qz - qw * qx);
    const float r20 = 2.0f * (qx * qz - qw * qy);
    const float r21 = 2.0f * (qy * qz + qw * qx);
    const float r22 = 1.0f - 2.0f * (qx * qx + qy * qy);

    const float si0 = 1.0f / (scales[3 * i + 0] + 1e-8f);
    const float si1 = 1.0f / (scales[3 * i + 1] + 1e-8f);
    const float si2 = 1.0f / (scales[3 * i + 2] + 1e-8f);

    // mahal = |M d|^2, rows of M: si_j * (column j of R)
    rec[4 * i + 0] = make_float4(c0, c1, c2, density[i]);
    rec[4 * i + 1] = make_float4(si0 * r00, si0 * r10, si0 * r20, 0.0f);
    rec[4 * i + 2] = make_float4(si1 * r01, si1 * r11, si1 * r21, 0.0f);
    rec[4 * i + 3] = make_float4(si2 * r02, si2 * r12, si2 * r22, 0.0f);
}

__device__ __forceinline__ void splat_site(
    float* tile, int k, int b0, int b1, int b2, int X0, int X1, int X2,
    const float4& r0, const float4& r1, const float4& r2, const float4& r3)
{
    // k in [0,125): site within the 5^3 window
    const int dz = k / 25;
    const int rm = k - dz * 25;
    const int dy = rm / 5;
    const int dx = rm - dy * 5;
    const int g0 = b0 + dz - 2;
    const int g1 = b1 + dy - 2;
    const int g2 = b2 + dx - 2;
    const int l0 = g0 - X0;
    const int l1 = g1 - X1;
    const int l2 = g2 - X2;
    // in-tile implies in-volume (tiles partition the volume exactly)
    if ((unsigned)l0 < W0 && (unsigned)l1 < W1 && (unsigned)l2 < W2) {
        const float d0 = ((float)g0 - r0.x) * (1.0f / 64.0f);
        const float d1 = ((float)g1 - r0.y) * (1.0f / 64.0f);
        const float d2 = ((float)g2 - r0.z) * (1.0f / 64.0f);
        const float m0 = r1.x * d0 + r1.y * d1 + r1.z * d2;
        const float m1 = r2.x * d0 + r2.y * d1 + r2.z * d2;
        const float m2 = r3.x * d0 + r3.y * d1 + r3.z * d2;
        const float mah = m0 * m0 + m1 * m1 + m2 * m2;
        if (mah <= 9.0f) {
            atomicAdd(&tile[(l0 * W1 + l1) * W2 + l2], __expf(-0.5f * mah) * r0.w);
        }
    }
}

__global__ __launch_bounds__(256) void voxelize_tiles(
    const unsigned int* __restrict__ packed,
    const float4* __restrict__ rec,
    float* __restrict__ volume,
    int n)
{
    __shared__ float tile[W0 * W1 * W2];   // 16 KB
    __shared__ int queue[CAP];             // 8 KB
    __shared__ int qn;

    const int t = threadIdx.x;
    const int X2 = blockIdx.x * W2;
    const int X1 = blockIdx.y * W1;
    const int X0 = blockIdx.z * W0;

    for (int v = t; v < W0 * W1 * W2; v += 256) tile[v] = 0.0f;
    if (t == 0) qn = 0;
    __syncthreads();

    // Phase 1: scan all points, queue those whose 5^3 window intersects tile.
    // Window [b-2, b+2] hits [X, X+W) iff b >= X-2 && b <= X+W+1.
#pragma unroll 4
    for (int p = t; p < n; p += 256) {
        const unsigned u = packed[p];
        const int b0 = u & 255;
        const int b1 = (u >> 8) & 255;
        const int b2 = (u >> 16) & 255;
        const bool hit = (b0 >= X0 - 2) & (b0 <= X0 + W0 + 1) &
                         (b1 >= X1 - 2) & (b1 <= X1 + W1 + 1) &
                         (b2 >= X2 - 2) & (b2 <= X2 + W2 + 1);
        if (hit) {
            const int slot = atomicAdd(&qn, 1);
            if (slot < CAP) {
                queue[slot] = p;
            } else {
                // overflow fallback (statistically never: ~412 expected, CAP=2048)
                const float4 r0 = rec[4 * p + 0];
                const float4 r1 = rec[4 * p + 1];
                const float4 r2 = rec[4 * p + 2];
                const float4 r3 = rec[4 * p + 3];
                for (int k = 0; k < 125; ++k)
                    splat_site(tile, k, b0, b1, b2, X0, X1, X2, r0, r1, r2, r3);
            }
        }
    }
    __syncthreads();
    int nq = qn; if (nq > CAP) nq = CAP;

    // Phase 2: drain queue. 128 threads (2 waves) per point: lane-uniform,
    // site k = t&127 (k<125 active), two points in flight per 256-thread pass.
    const int half = t >> 7;
    const int k = t & 127;
    for (int j = half; j < nq; j += 2) {
        const int p = queue[j];
        // broadcast loads: all 128 threads read the same record (one L2 txn each)
        const float4 r0 = rec[4 * p + 0];
        const float4 r1 = rec[4 * p + 1];
        const float4 r2 = rec[4 * p + 2];
        const float4 r3 = rec[4 * p + 3];
        const unsigned u = packed[p];
        const int b0 = u & 255;
        const int b1 = (u >> 8) & 255;
        const int b2 = (u >> 16) & 255;
        if (k < 125)
            splat_site(tile, k, b0, b1, b2, X0, X1, X2, r0, r1, r2, r3);
    }
    __syncthreads();

    // Write the tile: full 128B-line coalesced float4 stores, covers every voxel.
    const float4* tl4 = (const float4*)tile;
    for (int cid = t; cid < (W0 * W1 * W2) / 4; cid += 256) {
        const int l2q = cid & (W2 / 4 - 1);       // float4 chunk within row
        const int row = cid >> 3;                 // 0..127
        const int l1 = row & (W1 - 1);
        const int l0 = row >> 4;
        const int gelem = ((X0 + l0) * VOX + (X1 + l1)) * VOX + X2 + l2q * 4;
        ((float4*)volume)[gelem >> 2] = tl4[cid];
    }
}

extern "C" void kernel_launch(void* const* d_in, const int* in_sizes, int n_in,
                              void* d_out, int out_size, void* d_ws, size_t ws_size,
                              hipStream_t stream) {
    const float* positions = (const float*)d_in[0];
    const float* scales    = (const float*)d_in[1];
    const float* rotations = (const float*)d_in[2];
    const float* density   = (const float*)d_in[3];
    float* volume = (float*)d_out;

    const int n = in_sizes[0] / 3;

    unsigned int* packed = (unsigned int*)d_ws;                    // n * 4 B
    float4* rec = (float4*)((char*)d_ws + (1 << 20));              // n * 64 B

    prep_points<<<(n + 255) / 256, 256, 0, stream>>>(
        positions, scales, rotations, density, packed, rec, n);

    dim3 grid(VOX / W2, VOX / W1, VOX / W0);   // (4, 8, 16) = 512 blocks
    voxelize_tiles<<<grid, 256, 0, stream>>>(packed, rec, volume, n);
    // no memset: tiles partition the volume; every voxel is stored exactly once
}

// Round 7
// 135.666 us; speedup vs baseline: 2.3776x; 2.3776x over previous
//
#include <hip/hip_runtime.h>

// Voxelizer, round 7: binned tile-gather.
// R6 post-mortem: tile-gather was latency-bound (21% occupancy, 2 blocks/CU,
// 51.2M brute-force point-tests, serial dependent chains). This version bins
// points into per-tile lists first (avg 3.5 tiles/point), then 2048 tile
// blocks (8/CU) each drain only their own bin (~170 pts), evaluate only the
// clipped in-tile sites (12.5M total), accumulate in LDS (ds_add_f32, random
// banks), and write full-line coalesced float4 stores. No global atomics on
// the volume, no memset of the volume (tiles partition it exactly).

#define VOX 128
#define T0 4            // tile z extent
#define T1 8            // tile y extent
#define T2 32           // tile x extent (32 f32 = one 128 B line)
#define NT0 (VOX / T0)  // 32
#define NT1 (VOX / T1)  // 16
#define NT2 (VOX / T2)  // 4
#define NCELL (NT0 * NT1 * NT2)  // 2048
#define CAP 1024        // bin capacity; mean occupancy ~170, 6x headroom

// d_ws layout:
//   counts: NCELL * 4 B            @ 0        (memset to 0 each launch)
//   bins:   NCELL * CAP * 4 B      @ 1 MB     (8 MB)
//   rec:    n * 64 B               @ 16 MB    (6.4 MB)

__global__ __launch_bounds__(256) void bin_points(
    const float* __restrict__ positions,  // (N,3)
    const float* __restrict__ scales,     // (N,3)
    const float* __restrict__ rotations,  // (N,4) w,x,y,z
    const float* __restrict__ density,    // (N,)
    unsigned int* __restrict__ counts,    // (NCELL,)
    int* __restrict__ bins,               // (NCELL, CAP)
    float4* __restrict__ rec,             // (N,4)
    int n)
{
    const int i = blockIdx.x * blockDim.x + threadIdx.x;
    if (i >= n) return;

    const float c0 = (positions[3 * i + 0] + 1.0f) * 64.0f - 0.5f;
    const float c1 = (positions[3 * i + 1] + 1.0f) * 64.0f - 0.5f;
    const float c2 = (positions[3 * i + 2] + 1.0f) * 64.0f - 0.5f;

    float qw = rotations[4 * i + 0];
    float qx = rotations[4 * i + 1];
    float qy = rotations[4 * i + 2];
    float qz = rotations[4 * i + 3];
    const float qn = rsqrtf(qw * qw + qx * qx + qy * qy + qz * qz);
    qw *= qn; qx *= qn; qy *= qn; qz *= qn;

    const float r00 = 1.0f - 2.0f * (qy * qy + qz * qz);
    const float r01 = 2.0f * (qx * qy - qw * qz);
    const float r02 = 2.0f * (qx * qz + qw * qy);
    const float r10 = 2.0f * (qx * qy + qw * qz);
    const float r11 = 1.0f - 2.0f * (qx * qx + qz * qz);
    const float r12 = 2.0f * (qy * qz - qw * qx);
    const float r20 = 2.0f * (qx * qz - qw * qy);
    const float r21 = 2.0f * (qy * qz + qw * qx);
    const float r22 = 1.0f - 2.0f * (qx * qx + qy * qy);

    const float si0 = 1.0f / (scales[3 * i + 0] + 1e-8f);
    const float si1 = 1.0f / (scales[3 * i + 1] + 1e-8f);
    const float si2 = 1.0f / (scales[3 * i + 2] + 1e-8f);

    // mahal = |M d|^2; rows of M are si_j * (column j of R)
    rec[4 * i + 0] = make_float4(c0, c1, c2, density[i]);
    rec[4 * i + 1] = make_float4(si0 * r00, si0 * r10, si0 * r20, 0.0f);
    rec[4 * i + 2] = make_float4(si1 * r01, si1 * r11, si1 * r21, 0.0f);
    rec[4 * i + 3] = make_float4(si2 * r02, si2 * r12, si2 * r22, 0.0f);

    // base voxel (round half to even, matches jnp.round); b in [0,128]
    const int b0 = (int)rintf(c0);
    const int b1 = (int)rintf(c1);
    const int b2 = (int)rintf(c2);

    // tiles overlapped by the clamped 5^3 window [max(b-2,0), min(b+2,127)]
    const int z_lo = max(b0 - 2, 0) / T0, z_hi = min(b0 + 2, VOX - 1) / T0;
    const int y_lo = max(b1 - 2, 0) / T1, y_hi = min(b1 + 2, VOX - 1) / T1;
    const int x_lo = max(b2 - 2, 0) / T2, x_hi = min(b2 + 2, VOX - 1) / T2;

    for (int tz = z_lo; tz <= z_hi; ++tz)
        for (int ty = y_lo; ty <= y_hi; ++ty)
            for (int tx = x_lo; tx <= x_hi; ++tx) {
                const int cell = (tz * NT1 + ty) * NT2 + tx;
                const unsigned slot = atomicAdd(&counts[cell], 1u);
                if (slot < CAP) bins[cell * CAP + slot] = i;
            }
}

__global__ __launch_bounds__(256) void splat_tiles(
    const unsigned int* __restrict__ counts,
    const int* __restrict__ bins,
    const float4* __restrict__ rec,
    float* __restrict__ volume)
{
    __shared__ float tile[T0 * T1 * T2];  // 1024 f32 = 4 KB

    const int t = threadIdx.x;
    const int tx = blockIdx.x, ty = blockIdx.y, tz = blockIdx.z;
    const int X0 = tz * T0, X1 = ty * T1, X2 = tx * T2;
    const int cell = (tz * NT1 + ty) * NT2 + tx;

    for (int v = t; v < T0 * T1 * T2; v += 256) tile[v] = 0.0f;
    __syncthreads();

    int nq = (int)counts[cell];
    if (nq > CAP) nq = CAP;

    for (int j = t; j < nq; j += 256) {
        const int p = bins[cell * CAP + j];
        const float4 r0 = rec[4 * p + 0];  // c0,c1,c2,density
        const float4 r1 = rec[4 * p + 1];  // M row 0
        const float4 r2 = rec[4 * p + 2];  // M row 1
        const float4 r3 = rec[4 * p + 3];  // M row 2

        const int b0 = (int)rintf(r0.x);
        const int b1 = (int)rintf(r0.y);
        const int b2 = (int)rintf(r0.z);

        // clipped site ranges: window ∩ tile (tile is inside the volume)
        const int lo0 = max(b0 - 2, X0), hi0 = min(b0 + 2, X0 + T0 - 1);
        const int lo1 = max(b1 - 2, X1), hi1 = min(b1 + 2, X1 + T1 - 1);
        const int lo2 = max(b2 - 2, X2), hi2 = min(b2 + 2, X2 + T2 - 1);

        const float inv_half = 1.0f / 64.0f;
        for (int g0 = lo0; g0 <= hi0; ++g0) {
            const float d0 = ((float)g0 - r0.x) * inv_half;
            const float f0 = r1.x * d0;
            const float f1 = r2.x * d0;
            const float f2 = r3.x * d0;
            const int base0 = (g0 - X0) * T1;
            for (int g1 = lo1; g1 <= hi1; ++g1) {
                const float d1 = ((float)g1 - r0.y) * inv_half;
                const float e0 = f0 + r1.y * d1;
                const float e1 = f1 + r2.y * d1;
                const float e2 = f2 + r3.y * d1;
                const int base1 = (base0 + (g1 - X1)) * T2;
                for (int g2 = lo2; g2 <= hi2; ++g2) {
                    const float d2 = ((float)g2 - r0.z) * inv_half;
                    const float m0 = e0 + r1.z * d2;
                    const float m1 = e1 + r2.z * d2;
                    const float m2 = e2 + r3.z * d2;
                    const float mah = m0 * m0 + m1 * m1 + m2 * m2;
                    if (mah <= 9.0f) {
                        atomicAdd(&tile[base1 + (g2 - X2)],
                                  __expf(-0.5f * mah) * r0.w);
                    }
                }
            }
        }
    }
    __syncthreads();

    // store: 1024 f32 = 256 float4 = 32 full 128 B lines, fully coalesced
    const float4* tl4 = (const float4*)tile;
    const int row = t >> 3;        // 0..31 : (l0,l1)
    const int ch  = t & 7;         // float4 chunk within the 32-f32 row
    const int l0 = row >> 3;
    const int l1 = row & 7;
    const int g = ((X0 + l0) * VOX + (X1 + l1)) * VOX + X2 + ch * 4;
    ((float4*)volume)[g >> 2] = tl4[t];
}

extern "C" void kernel_launch(void* const* d_in, const int* in_sizes, int n_in,
                              void* d_out, int out_size, void* d_ws, size_t ws_size,
                              hipStream_t stream) {
    const float* positions = (const float*)d_in[0];
    const float* scales    = (const float*)d_in[1];
    const float* rotations = (const float*)d_in[2];
    const float* density   = (const float*)d_in[3];
    float* volume = (float*)d_out;

    const int n = in_sizes[0] / 3;

    unsigned int* counts = (unsigned int*)d_ws;
    int* bins            = (int*)((char*)d_ws + (1 << 20));
    float4* rec          = (float4*)((char*)d_ws + (16 << 20));

    hipMemsetAsync(counts, 0, NCELL * sizeof(unsigned int), stream);

    bin_points<<<(n + 255) / 256, 256, 0, stream>>>(
        positions, scales, rotations, density, counts, bins, rec, n);

    dim3 grid(NT2, NT1, NT0);  // (4, 16, 32) = 2048 blocks
    splat_tiles<<<grid, 256, 0, stream>>>(counts, bins, rec, volume);
    // no volume memset: every voxel is stored exactly once by splat_tiles
}

// Round 8
// 128.068 us; speedup vs baseline: 2.5186x; 1.0593x over previous
//
#include <hip/hip_runtime.h>

// Voxelizer, round 8: single-cell binning + 27-neighbor tile gather.
// Model from R3/R4/R7 counters: device-scope scattered atomics write through
// to HBM (~64 B line per op) and that path runs at ~550 GB/s; kernel time ~
// atomic_count * 64B / 550GB/s regardless of occupancy/VALU. So: bin with ONE
// atomic per point (base-voxel cell), pack {idx, local base voxel} in the bin
// entry, and let each tile block scan its <=27 neighbor cells' segments with a
// flattened LDS segment table. LDS-accumulated tile, dense float4 stores.

#define VOX 128
#define T0 4            // tile z extent
#define T1 8            // tile y extent
#define T2 32           // tile x extent (one 128 B line)
#define NT0 (VOX / T0)  // 32
#define NT1 (VOX / T1)  // 16
#define NT2 (VOX / T2)  // 4
#define NCELL (NT0 * NT1 * NT2)  // 2048
#define CAP 256         // mean 49 pts/cell, ~5 sigma headroom

// d_ws layout:
//   counts: NCELL * 4 B          @ 0       (memset to 0 each launch)
//   bins:   NCELL * CAP * 4 B    @ 64 KB   (2 MB)
//   rec:    n * 64 B             @ 4 MB    (6.4 MB)

__global__ __launch_bounds__(256) void bin_points(
    const float* __restrict__ positions,  // (N,3)
    const float* __restrict__ scales,     // (N,3)
    const float* __restrict__ rotations,  // (N,4) w,x,y,z
    const float* __restrict__ density,    // (N,)
    unsigned int* __restrict__ counts,    // (NCELL,)
    unsigned int* __restrict__ bins,      // (NCELL, CAP) packed entries
    float4* __restrict__ rec,             // (N,4)
    int n)
{
    const int i = blockIdx.x * blockDim.x + threadIdx.x;
    if (i >= n) return;

    const float c0 = (positions[3 * i + 0] + 1.0f) * 64.0f - 0.5f;
    const float c1 = (positions[3 * i + 1] + 1.0f) * 64.0f - 0.5f;
    const float c2 = (positions[3 * i + 2] + 1.0f) * 64.0f - 0.5f;

    float qw = rotations[4 * i + 0];
    float qx = rotations[4 * i + 1];
    float qy = rotations[4 * i + 2];
    float qz = rotations[4 * i + 3];
    const float qn = rsqrtf(qw * qw + qx * qx + qy * qy + qz * qz);
    qw *= qn; qx *= qn; qy *= qn; qz *= qn;

    const float r00 = 1.0f - 2.0f * (qy * qy + qz * qz);
    const float r01 = 2.0f * (qx * qy - qw * qz);
    const float r02 = 2.0f * (qx * qz + qw * qy);
    const float r10 = 2.0f * (qx * qy + qw * qz);
    const float r11 = 1.0f - 2.0f * (qx * qx + qz * qz);
    const float r12 = 2.0f * (qy * qz - qw * qx);
    const float r20 = 2.0f * (qx * qz - qw * qy);
    const float r21 = 2.0f * (qy * qz + qw * qx);
    const float r22 = 1.0f - 2.0f * (qx * qx + qy * qy);

    const float si0 = 1.0f / (scales[3 * i + 0] + 1e-8f);
    const float si1 = 1.0f / (scales[3 * i + 1] + 1e-8f);
    const float si2 = 1.0f / (scales[3 * i + 2] + 1e-8f);

    // mahal = |M d|^2; rows of M are si_j * (column j of R)
    rec[4 * i + 0] = make_float4(c0, c1, c2, density[i]);
    rec[4 * i + 1] = make_float4(si0 * r00, si0 * r10, si0 * r20, 0.0f);
    rec[4 * i + 2] = make_float4(si1 * r01, si1 * r11, si1 * r21, 0.0f);
    rec[4 * i + 3] = make_float4(si2 * r02, si2 * r12, si2 * r22, 0.0f);

    // base voxel (round half to even, matches jnp.round); b in [0,127]
    const int b0 = (int)rintf(c0);
    const int b1 = (int)rintf(c1);
    const int b2 = (int)rintf(c2);

    // single owning cell; pack {idx(17b), l0(2b), l1(3b), l2(5b)}
    const int cell = ((b0 / T0) * NT1 + (b1 / T1)) * NT2 + (b2 / T2);
    const unsigned entry = (unsigned)i |
                           ((unsigned)(b0 & (T0 - 1)) << 17) |
                           ((unsigned)(b1 & (T1 - 1)) << 19) |
                           ((unsigned)(b2 & (T2 - 1)) << 22);
    const unsigned slot = atomicAdd(&counts[cell], 1u);
    if (slot < CAP) bins[cell * CAP + slot] = entry;
}

__global__ __launch_bounds__(256) void splat_tiles(
    const unsigned int* __restrict__ counts,
    const unsigned int* __restrict__ bins,
    const float4* __restrict__ rec,
    float* __restrict__ volume)
{
    __shared__ float tile[T0 * T1 * T2];   // 4 KB
    __shared__ int seg_cell[27];
    __shared__ int seg_start[28];
    __shared__ int seg_total;

    const int t = threadIdx.x;
    const int tx = blockIdx.x, ty = blockIdx.y, tz = blockIdx.z;
    const int X0 = tz * T0, X1 = ty * T1, X2 = tx * T2;

    for (int v = t; v < T0 * T1 * T2; v += 256) tile[v] = 0.0f;

    // neighbor cell ranges (clamped, no duplicates)
    const int z0 = max(tz - 1, 0), z1 = min(tz + 1, NT0 - 1);
    const int y0 = max(ty - 1, 0), y1 = min(ty + 1, NT1 - 1);
    const int x0 = max(tx - 1, 0), x1 = min(tx + 1, NT2 - 1);
    const int nz = z1 - z0 + 1, ny = y1 - y0 + 1, nx = x1 - x0 + 1;
    const int ncells = nz * ny * nx;

    if (t < ncells) {
        const int kz = t / (ny * nx);
        const int r  = t - kz * (ny * nx);
        const int ky = r / nx;
        const int kx = r - ky * nx;
        const int cell = ((z0 + kz) * NT1 + (y0 + ky)) * NT2 + (x0 + kx);
        seg_cell[t] = cell;
        int c = (int)counts[cell];
        seg_start[t] = (c > CAP) ? CAP : c;   // temporarily hold counts
    }
    __syncthreads();
    if (t == 0) {
        int acc = 0;
        for (int k = 0; k < ncells; ++k) {
            const int c = seg_start[k];
            seg_start[k] = acc;
            acc += c;
        }
        seg_start[ncells] = acc;
        seg_total = acc;
    }
    __syncthreads();

    const int total = seg_total;
    const float inv_half = 1.0f / 64.0f;
    int s = 0;
    for (int j = t; j < total; j += 256) {
        while (j >= seg_start[s + 1]) ++s;
        const int cell = seg_cell[s];
        const unsigned e = bins[cell * CAP + (j - seg_start[s])];

        // decode base voxel from cell + local offsets
        const int cz = cell / (NT1 * NT2);
        const int cr = cell - cz * (NT1 * NT2);
        const int cy = cr / NT2;
        const int cx = cr - cy * NT2;
        const int b0 = cz * T0 + ((e >> 17) & (T0 - 1));
        const int b1 = cy * T1 + ((e >> 19) & (T1 - 1));
        const int b2 = cx * T2 + ((e >> 22) & (T2 - 1));

        // does the 5^3 window touch this tile?
        const bool hit = (b0 >= X0 - 2) & (b0 <= X0 + T0 + 1) &
                         (b1 >= X1 - 2) & (b1 <= X1 + T1 + 1) &
                         (b2 >= X2 - 2) & (b2 <= X2 + T2 + 1);
        if (!hit) continue;

        const int p = (int)(e & 0x1FFFFu);
        const float4 r0 = rec[4 * p + 0];  // c0,c1,c2,density
        const float4 r1 = rec[4 * p + 1];  // M row 0
        const float4 r2 = rec[4 * p + 2];  // M row 1
        const float4 r3 = rec[4 * p + 3];  // M row 2

        const int lo0 = max(b0 - 2, X0), hi0 = min(b0 + 2, X0 + T0 - 1);
        const int lo1 = max(b1 - 2, X1), hi1 = min(b1 + 2, X1 + T1 - 1);
        const int lo2 = max(b2 - 2, X2), hi2 = min(b2 + 2, X2 + T2 - 1);

        for (int g0 = lo0; g0 <= hi0; ++g0) {
            const float d0 = ((float)g0 - r0.x) * inv_half;
            const float f0 = r1.x * d0;
            const float f1 = r2.x * d0;
            const float f2 = r3.x * d0;
            const int base0 = (g0 - X0) * T1;
            for (int g1 = lo1; g1 <= hi1; ++g1) {
                const float d1 = ((float)g1 - r0.y) * inv_half;
                const float e0 = f0 + r1.y * d1;
                const float e1 = f1 + r2.y * d1;
                const float e2 = f2 + r3.y * d1;
                const int base1 = (base0 + (g1 - X1)) * T2;
                for (int g2 = lo2; g2 <= hi2; ++g2) {
                    const float d2 = ((float)g2 - r0.z) * inv_half;
                    const float m0 = e0 + r1.z * d2;
                    const float m1 = e1 + r2.z * d2;
                    const float m2 = e2 + r3.z * d2;
                    const float mah = m0 * m0 + m1 * m1 + m2 * m2;
                    if (mah <= 9.0f) {
                        atomicAdd(&tile[base1 + (g2 - X2)],
                                  __expf(-0.5f * mah) * r0.w);
                    }
                }
            }
        }
    }
    __syncthreads();

    // store: 1024 f32 = 256 float4 = 32 full 128 B lines, fully coalesced
    const float4* tl4 = (const float4*)tile;
    const int row = t >> 3;        // 0..31 : (l0,l1)
    const int ch  = t & 7;         // float4 chunk within the 32-f32 row
    const int l0 = row >> 3;
    const int l1 = row & 7;
    const int g = ((X0 + l0) * VOX + (X1 + l1)) * VOX + X2 + ch * 4;
    ((float4*)volume)[g >> 2] = tl4[t];
}

extern "C" void kernel_launch(void* const* d_in, const int* in_sizes, int n_in,
                              void* d_out, int out_size, void* d_ws, size_t ws_size,
                              hipStream_t stream) {
    const float* positions = (const float*)d_in[0];
    const float* scales    = (const float*)d_in[1];
    const float* rotations = (const float*)d_in[2];
    const float* density   = (const float*)d_in[3];
    float* volume = (float*)d_out;

    const int n = in_sizes[0] / 3;

    unsigned int* counts = (unsigned int*)d_ws;
    unsigned int* bins   = (unsigned int*)((char*)d_ws + (64 << 10));
    float4* rec          = (float4*)((char*)d_ws + (4 << 20));

    hipMemsetAsync(counts, 0, NCELL * sizeof(unsigned int), stream);

    bin_points<<<(n + 255) / 256, 256, 0, stream>>>(
        positions, scales, rotations, density, counts, bins, rec, n);

    dim3 grid(NT2, NT1, NT0);  // (4, 16, 32) = 2048 blocks
    splat_tiles<<<grid, 256, 0, stream>>>(counts, bins, rec, volume);
    // no volume memset: every voxel is stored exactly once by splat_tiles
}

// Round 9
// 103.489 us; speedup vs baseline: 3.1168x; 1.2375x over previous
//
#include <hip/hip_runtime.h>

// Voxelizer, round 9: R8 + two-phase compaction in splat_tiles.
// R8 counters: splat_tiles 50us, VALUBusy 65%, occ 46% -> VALU-issue-bound on
// WASTED issue: 27-cell halo scan has ~13% hit rate, and hit lanes run the
// divergent clipped splat while ~87% of the wave idles; plus int divisions in
// the per-candidate cell decode. This round: phase A hit-tests (division-free,
// packed cell origins in the segment table) and compacts accepted work at
// (point, z-plane) granularity into an LDS queue; phase B drains it with all
// lanes holding real work. bin_points unchanged (1 atomic/pt, ~14us,
// write-through floor 100k*64B/550GB/s).

#define VOX 128
#define T0 4            // tile z extent
#define T1 8            // tile y extent
#define T2 32           // tile x extent (one 128 B line)
#define NT0 (VOX / T0)  // 32
#define NT1 (VOX / T1)  // 16
#define NT2 (VOX / T2)  // 4
#define NCELL (NT0 * NT1 * NT2)  // 2048
#define CAP 256         // bin capacity; mean 49 pts/cell
#define CAPQ 1280       // plane-item queue; mean ~425/block

// d_ws layout:
//   counts: NCELL * 4 B          @ 0       (memset to 0 each launch)
//   bins:   NCELL * CAP * 4 B    @ 64 KB   (2 MB)
//   rec:    n * 64 B             @ 4 MB    (6.4 MB)

__global__ __launch_bounds__(256) void bin_points(
    const float* __restrict__ positions,  // (N,3)
    const float* __restrict__ scales,     // (N,3)
    const float* __restrict__ rotations,  // (N,4) w,x,y,z
    const float* __restrict__ density,    // (N,)
    unsigned int* __restrict__ counts,    // (NCELL,)
    unsigned int* __restrict__ bins,      // (NCELL, CAP) packed entries
    float4* __restrict__ rec,             // (N,4)
    int n)
{
    const int i = blockIdx.x * blockDim.x + threadIdx.x;
    if (i >= n) return;

    const float c0 = (positions[3 * i + 0] + 1.0f) * 64.0f - 0.5f;
    const float c1 = (positions[3 * i + 1] + 1.0f) * 64.0f - 0.5f;
    const float c2 = (positions[3 * i + 2] + 1.0f) * 64.0f - 0.5f;

    float qw = rotations[4 * i + 0];
    float qx = rotations[4 * i + 1];
    float qy = rotations[4 * i + 2];
    float qz = rotations[4 * i + 3];
    const float qn = rsqrtf(qw * qw + qx * qx + qy * qy + qz * qz);
    qw *= qn; qx *= qn; qy *= qn; qz *= qn;

    const float r00 = 1.0f - 2.0f * (qy * qy + qz * qz);
    const float r01 = 2.0f * (qx * qy - qw * qz);
    const float r02 = 2.0f * (qx * qz + qw * qy);
    const float r10 = 2.0f * (qx * qy + qw * qz);
    const float r11 = 1.0f - 2.0f * (qx * qx + qz * qz);
    const float r12 = 2.0f * (qy * qz - qw * qx);
    const float r20 = 2.0f * (qx * qz - qw * qy);
    const float r21 = 2.0f * (qy * qz + qw * qx);
    const float r22 = 1.0f - 2.0f * (qx * qx + qy * qy);

    const float si0 = 1.0f / (scales[3 * i + 0] + 1e-8f);
    const float si1 = 1.0f / (scales[3 * i + 1] + 1e-8f);
    const float si2 = 1.0f / (scales[3 * i + 2] + 1e-8f);

    // mahal = |M d|^2; rows of M are si_j * (column j of R)
    rec[4 * i + 0] = make_float4(c0, c1, c2, density[i]);
    rec[4 * i + 1] = make_float4(si0 * r00, si0 * r10, si0 * r20, 0.0f);
    rec[4 * i + 2] = make_float4(si1 * r01, si1 * r11, si1 * r21, 0.0f);
    rec[4 * i + 3] = make_float4(si2 * r02, si2 * r12, si2 * r22, 0.0f);

    // base voxel (round half to even, matches jnp.round); b in [0,127]
    const int b0 = (int)rintf(c0);
    const int b1 = (int)rintf(c1);
    const int b2 = (int)rintf(c2);

    // single owning cell; pack {idx(17b), l0(2b), l1(3b), l2(5b)}
    const int cell = ((b0 / T0) * NT1 + (b1 / T1)) * NT2 + (b2 / T2);
    const unsigned entry = (unsigned)i |
                           ((unsigned)(b0 & (T0 - 1)) << 17) |
                           ((unsigned)(b1 & (T1 - 1)) << 19) |
                           ((unsigned)(b2 & (T2 - 1)) << 22);
    const unsigned slot = atomicAdd(&counts[cell], 1u);
    if (slot < CAP) bins[cell * CAP + slot] = entry;
}

__global__ __launch_bounds__(256) void splat_tiles(
    const unsigned int* __restrict__ counts,
    const unsigned int* __restrict__ bins,
    const float4* __restrict__ rec,
    float* __restrict__ volume)
{
    __shared__ float tile[T0 * T1 * T2];   // 4 KB
    __shared__ int seg_cell[27];           // cell index of each segment
    __shared__ int seg_base[27];           // packed cell origin: z<<16|y<<8|x
    __shared__ int seg_start[28];
    __shared__ unsigned queue[CAPQ];       // 5 KB: compacted (point, plane) items
    __shared__ int qcount;

    const int t = threadIdx.x;
    const int tx = blockIdx.x, ty = blockIdx.y, tz = blockIdx.z;
    const int X0 = tz * T0, X1 = ty * T1, X2 = tx * T2;

    for (int v = t; v < T0 * T1 * T2; v += 256) tile[v] = 0.0f;
    if (t == 0) qcount = 0;

    // neighbor cell ranges (clamped, no duplicates)
    const int z0 = max(tz - 1, 0), z1 = min(tz + 1, NT0 - 1);
    const int y0 = max(ty - 1, 0), y1 = min(ty + 1, NT1 - 1);
    const int x0 = max(tx - 1, 0), x1 = min(tx + 1, NT2 - 1);
    const int nz = z1 - z0 + 1, ny = y1 - y0 + 1, nx = x1 - x0 + 1;
    const int ncells = nz * ny * nx;

    if (t < ncells) {
        const int kz = t / (ny * nx);
        const int r  = t - kz * (ny * nx);
        const int ky = r / nx;
        const int kx = r - ky * nx;
        const int cz = z0 + kz, cy = y0 + ky, cx = x0 + kx;
        const int cell = (cz * NT1 + cy) * NT2 + cx;
        seg_cell[t] = cell;
        seg_base[t] = (cz * T0 << 16) | (cy * T1 << 8) | (cx * T2);
        int c = (int)counts[cell];
        seg_start[t] = (c > CAP) ? CAP : c;   // temporarily hold counts
    }
    __syncthreads();
    if (t == 0) {
        int acc = 0;
        for (int k = 0; k < ncells; ++k) {
            const int c = seg_start[k];
            seg_start[k] = acc;
            acc += c;
        }
        seg_start[ncells] = acc;
    }
    __syncthreads();

    // ---- Phase A: hit-test all halo candidates, compact (point, plane) items
    const int total = seg_start[ncells];
    int s = 0;
    for (int j = t; j < total; j += 256) {
        while (j >= seg_start[s + 1]) ++s;
        const unsigned e = bins[seg_cell[s] * CAP + (j - seg_start[s])];
        const int sb = seg_base[s];
        const int b0 = ((sb >> 16) & 255) + ((e >> 17) & (T0 - 1));
        const int b1 = ((sb >> 8) & 255) + ((e >> 19) & (T1 - 1));
        const int b2 = (sb & 255) + ((e >> 22) & (T2 - 1));

        const int lo0 = max(b0 - 2, X0), hi0 = min(b0 + 2, X0 + T0 - 1);
        const bool hit1 = (b1 >= X1 - 2) & (b1 <= X1 + T1 + 1);
        const bool hit2 = (b2 >= X2 - 2) & (b2 <= X2 + T2 + 1);
        if (lo0 > hi0 || !hit1 || !hit2) continue;

        const unsigned p = e & 0x1FFFFu;
        const unsigned rel1 = (unsigned)(b1 - (X1 - 2));   // 0..T1+3  (4 bits)
        const unsigned rel2 = (unsigned)(b2 - (X2 - 2));   // 0..T2+3  (6 bits)
        for (int g0 = lo0; g0 <= hi0; ++g0) {
            const unsigned item = p | ((unsigned)(g0 - X0) << 17) |
                                  (rel1 << 19) | (rel2 << 23);
            const int slot = atomicAdd(&qcount, 1);
            if (slot < CAPQ) queue[slot] = item;
            // overflow statistically impossible (mean ~425, cap 1280); if it
            // ever happened the item is dropped -- acceptable only if it can't
            // happen, so CAPQ is sized with >40 sigma of headroom.
        }
    }
    __syncthreads();

    // ---- Phase B: dense drain; every lane holds a real (point, plane) splat
    int nq = qcount; if (nq > CAPQ) nq = CAPQ;
    const float inv_half = 1.0f / 64.0f;
    for (int j = t; j < nq; j += 256) {
        const unsigned item = queue[j];
        const int p  = (int)(item & 0x1FFFFu);
        const int g0 = X0 + (int)((item >> 17) & 3u);
        const int b1 = X1 - 2 + (int)((item >> 19) & 15u);
        const int b2 = X2 - 2 + (int)((item >> 23) & 63u);

        const float4 r0 = rec[4 * p + 0];  // c0,c1,c2,density
        const float4 r1 = rec[4 * p + 1];  // M row 0
        const float4 r2 = rec[4 * p + 2];  // M row 1
        const float4 r3 = rec[4 * p + 3];  // M row 2

        const int lo1 = max(b1 - 2, X1), hi1 = min(b1 + 2, X1 + T1 - 1);
        const int lo2 = max(b2 - 2, X2), hi2 = min(b2 + 2, X2 + T2 - 1);

        const float d0 = ((float)g0 - r0.x) * inv_half;
        const float f0 = r1.x * d0;
        const float f1 = r2.x * d0;
        const float f2 = r3.x * d0;
        const int base0 = (g0 - X0) * T1;

        for (int g1 = lo1; g1 <= hi1; ++g1) {
            const float d1 = ((float)g1 - r0.y) * inv_half;
            const float e0 = f0 + r1.y * d1;
            const float e1 = f1 + r2.y * d1;
            const float e2 = f2 + r3.y * d1;
            const int base1 = (base0 + (g1 - X1)) * T2;
            for (int g2 = lo2; g2 <= hi2; ++g2) {
                const float d2 = ((float)g2 - r0.z) * inv_half;
                const float m0 = e0 + r1.z * d2;
                const float m1 = e1 + r2.z * d2;
                const float m2 = e2 + r3.z * d2;
                const float mah = m0 * m0 + m1 * m1 + m2 * m2;
                if (mah <= 9.0f) {
                    atomicAdd(&tile[base1 + (g2 - X2)],
                              __expf(-0.5f * mah) * r0.w);
                }
            }
        }
    }
    __syncthreads();

    // store: 1024 f32 = 256 float4 = 32 full 128 B lines, fully coalesced
    const float4* tl4 = (const float4*)tile;
    const int row = t >> 3;        // 0..31 : (l0,l1)
    const int ch  = t & 7;         // float4 chunk within the 32-f32 row
    const int l0 = row >> 3;
    const int l1 = row & 7;
    const int g = ((X0 + l0) * VOX + (X1 + l1)) * VOX + X2 + ch * 4;
    ((float4*)volume)[g >> 2] = tl4[t];
}

extern "C" void kernel_launch(void* const* d_in, const int* in_sizes, int n_in,
                              void* d_out, int out_size, void* d_ws, size_t ws_size,
                              hipStream_t stream) {
    const float* positions = (const float*)d_in[0];
    const float* scales    = (const float*)d_in[1];
    const float* rotations = (const float*)d_in[2];
    const float* density   = (const float*)d_in[3];
    float* volume = (float*)d_out;

    const int n = in_sizes[0] / 3;

    unsigned int* counts = (unsigned int*)d_ws;
    unsigned int* bins   = (unsigned int*)((char*)d_ws + (64 << 10));
    float4* rec          = (float4*)((char*)d_ws + (4 << 20));

    hipMemsetAsync(counts, 0, NCELL * sizeof(unsigned int), stream);

    bin_points<<<(n + 255) / 256, 256, 0, stream>>>(
        positions, scales, rotations, density, counts, bins, rec, n);

    dim3 grid(NT2, NT1, NT0);  // (4, 16, 32) = 2048 blocks
    splat_tiles<<<grid, 256, 0, stream>>>(counts, bins, rec, volume);
    // no volume memset: every voxel is stored exactly once by splat_tiles
}

// Round 10
// 100.424 us; speedup vs baseline: 3.2119x; 1.0305x over previous
//
#include <hip/hip_runtime.h>

// Voxelizer, round 10: de-serialize splat_tiles.
// R9: splat ~27us despite ~1us of useful issue. Enumerated stalls: serial
// t==0 prefix sum (all waves barriered), same-address LDS atomic queue push
// (up to 4 serialized/lane), 8 blocks/CU cap (256-thr blocks), dependent
// gathers between barriers. This round: 128-thr blocks, tile 4x8x16 (4096
// blocks, 16/CU, full 32-wave occupancy), single-wave shuffle prefix scan,
// per-wave private queues with in-register base (zero queue atomics), rec in
// 48B symmetric cov_inv form (3 gathers -> 2 extra + r0). bin_points keeps
// 1 global atomic/pt (write-through floor ~12us).

#define VOX 128
#define T0 4
#define T1 8
#define T2 16
#define NT0 (VOX / T0)   // 32
#define NT1 (VOX / T1)   // 16
#define NT2 (VOX / T2)   // 8
#define NCELL (NT0 * NT1 * NT2)   // 4096
#define CAP 128          // bin capacity; mean 24.4 pts/cell
#define WQ 512           // per-wave queue capacity (2 waves/block)

// d_ws layout:
//   counts: NCELL * 4 B          @ 0       (memset to 0 each launch)
//   bins:   NCELL * CAP * 4 B    @ 64 KB   (2 MB)
//   rec:    n * 48 B             @ 4 MB    (4.8 MB)

__global__ __launch_bounds__(256) void bin_points(
    const float* __restrict__ positions,  // (N,3)
    const float* __restrict__ scales,     // (N,3)
    const float* __restrict__ rotations,  // (N,4) w,x,y,z
    const float* __restrict__ density,    // (N,)
    unsigned int* __restrict__ counts,    // (NCELL,)
    unsigned int* __restrict__ bins,      // (NCELL, CAP) packed entries
    float4* __restrict__ rec,             // (N,3) 48 B/pt
    int n)
{
    const int i = blockIdx.x * blockDim.x + threadIdx.x;
    if (i >= n) return;

    const float c0 = (positions[3 * i + 0] + 1.0f) * 64.0f - 0.5f;
    const float c1 = (positions[3 * i + 1] + 1.0f) * 64.0f - 0.5f;
    const float c2 = (positions[3 * i + 2] + 1.0f) * 64.0f - 0.5f;

    float qw = rotations[4 * i + 0];
    float qx = rotations[4 * i + 1];
    float qy = rotations[4 * i + 2];
    float qz = rotations[4 * i + 3];
    const float qn = rsqrtf(qw * qw + qx * qx + qy * qy + qz * qz);
    qw *= qn; qx *= qn; qy *= qn; qz *= qn;

    const float r00 = 1.0f - 2.0f * (qy * qy + qz * qz);
    const float r01 = 2.0f * (qx * qy - qw * qz);
    const float r02 = 2.0f * (qx * qz + qw * qy);
    const float r10 = 2.0f * (qx * qy + qw * qz);
    const float r11 = 1.0f - 2.0f * (qx * qx + qz * qz);
    const float r12 = 2.0f * (qy * qz - qw * qx);
    const float r20 = 2.0f * (qx * qz - qw * qy);
    const float r21 = 2.0f * (qy * qz + qw * qx);
    const float r22 = 1.0f - 2.0f * (qx * qx + qy * qy);

    const float si0 = 1.0f / (scales[3 * i + 0] + 1e-8f);
    const float si1 = 1.0f / (scales[3 * i + 1] + 1e-8f);
    const float si2 = 1.0f / (scales[3 * i + 2] + 1e-8f);
    const float w0 = si0 * si0, w1 = si1 * si1, w2 = si2 * si2;

    // cov_inv A = R diag(si^2) R^T (symmetric, 6 unique)
    const float A00 = w0 * r00 * r00 + w1 * r01 * r01 + w2 * r02 * r02;
    const float A11 = w0 * r10 * r10 + w1 * r11 * r11 + w2 * r12 * r12;
    const float A22 = w0 * r20 * r20 + w1 * r21 * r21 + w2 * r22 * r22;
    const float A01 = w0 * r00 * r10 + w1 * r01 * r11 + w2 * r02 * r12;
    const float A02 = w0 * r00 * r20 + w1 * r01 * r21 + w2 * r02 * r22;
    const float A12 = w0 * r10 * r20 + w1 * r11 * r21 + w2 * r12 * r22;

    rec[3 * i + 0] = make_float4(c0, c1, c2, density[i]);
    rec[3 * i + 1] = make_float4(A00, A11, A22, A01);
    rec[3 * i + 2] = make_float4(A02, A12, 0.0f, 0.0f);

    // base voxel (round half to even, matches jnp.round); b in [0,127]
    const int b0 = (int)rintf(c0);
    const int b1 = (int)rintf(c1);
    const int b2 = (int)rintf(c2);

    // single owning cell; pack {idx(17b), l0(2b), l1(3b), l2(4b)}
    const int cell = ((b0 / T0) * NT1 + (b1 / T1)) * NT2 + (b2 / T2);
    const unsigned entry = (unsigned)i |
                           ((unsigned)(b0 & (T0 - 1)) << 17) |
                           ((unsigned)(b1 & (T1 - 1)) << 19) |
                           ((unsigned)(b2 & (T2 - 1)) << 22);
    const unsigned slot = atomicAdd(&counts[cell], 1u);
    if (slot < CAP) bins[cell * CAP + slot] = entry;
}

__global__ __launch_bounds__(128) void splat_tiles(
    const unsigned int* __restrict__ counts,
    const unsigned int* __restrict__ bins,
    const float4* __restrict__ rec,
    float* __restrict__ volume)
{
    __shared__ float tile[T0 * T1 * T2];   // 512 f32 = 2 KB
    __shared__ int seg_cell[27];
    __shared__ int seg_base[27];           // packed cell origin z<<16|y<<8|x
    __shared__ int seg_start[28];
    __shared__ unsigned queue[2 * WQ];     // 4 KB, per-wave halves
    __shared__ int qcount[2];

    const int t = threadIdx.x;             // 0..127 (2 waves)
    const int lane = t & 63;
    const int wv = t >> 6;
    const int tx = blockIdx.x, ty = blockIdx.y, tz = blockIdx.z;
    const int X0 = tz * T0, X1 = ty * T1, X2 = tx * T2;

    for (int v = t; v < T0 * T1 * T2; v += 128) tile[v] = 0.0f;

    // neighbor cells (clamped)
    const int z0 = max(tz - 1, 0), z1 = min(tz + 1, NT0 - 1);
    const int y0 = max(ty - 1, 0), y1 = min(ty + 1, NT1 - 1);
    const int x0 = max(tx - 1, 0), x1 = min(tx + 1, NT2 - 1);
    const int nz = z1 - z0 + 1, ny = y1 - y0 + 1, nx = x1 - x0 + 1;
    const int ncells = nz * ny * nx;

    if (t < ncells) {
        const int kz = t / (ny * nx);
        const int r  = t - kz * (ny * nx);
        const int ky = r / nx;
        const int kx = r - ky * nx;
        const int cz = z0 + kz, cy = y0 + ky, cx = x0 + kx;
        const int cell = (cz * NT1 + cy) * NT2 + cx;
        seg_cell[t] = cell;
        seg_base[t] = (cz * T0 << 16) | (cy * T1 << 8) | (cx * T2);
        int c = (int)counts[cell];
        seg_start[t] = (c > CAP) ? CAP : c;   // counts, pre-scan
    }
    __syncthreads();

    // wave-0 shuffle inclusive scan over <=27 segment counts (no serial loop)
    if (t < 64) {
        int v = (t < ncells) ? seg_start[t] : 0;
        int inc = v;
#pragma unroll
        for (int off = 1; off < 32; off <<= 1) {
            const int u = __shfl_up(inc, off, 64);
            if (lane >= off) inc += u;
        }
        if (t < ncells) seg_start[t + 1] = inc;
        if (t == 0) seg_start[0] = 0;
    }
    __syncthreads();

    // ---- Phase A: hit-test halo candidates, compact (point, plane) items
    // into per-wave private queue regions (zero atomics: shuffle scan + reg base)
    const int total = seg_start[ncells];
    int s = 0;
    int wbase = 0;
    for (int jb = wv * 64; jb < total; jb += 128) {
        const int j = jb + lane;
        const bool active = j < total;
        int np = 0;
        unsigned base_item = 0;
        if (active) {
            while (j >= seg_start[s + 1]) ++s;
            const unsigned e = bins[seg_cell[s] * CAP + (j - seg_start[s])];
            const int sb = seg_base[s];
            const int b0 = ((sb >> 16) & 255) + ((e >> 17) & (T0 - 1));
            const int b1 = ((sb >> 8) & 255) + ((e >> 19) & (T1 - 1));
            const int b2 = (sb & 255) + ((e >> 22) & (T2 - 1));
            const int lo0 = max(b0 - 2, X0), hi0 = min(b0 + 2, X0 + T0 - 1);
            const bool hit = (lo0 <= hi0) &
                             (b1 >= X1 - 2) & (b1 <= X1 + T1 + 1) &
                             (b2 >= X2 - 2) & (b2 <= X2 + T2 + 1);
            if (hit) {
                np = hi0 - lo0 + 1;   // 1..4 planes
                base_item = (e & 0x1FFFFu) |
                            ((unsigned)(lo0 - X0) << 17) |
                            ((unsigned)(b1 - (X1 - 2)) << 19) |
                            ((unsigned)(b2 - (X2 - 2)) << 23);
            }
        }
        // 64-lane exclusive scan of np
        int inc = np;
#pragma unroll
        for (int off = 1; off < 64; off <<= 1) {
            const int u = __shfl_up(inc, off, 64);
            if (lane >= off) inc += u;
        }
        const int excl = inc - np;
        const int tot = __shfl(inc, 63, 64);
        for (int k = 0; k < np; ++k) {
            const int slot = wbase + excl + k;
            if (slot < WQ)
                queue[wv * WQ + slot] = base_item + ((unsigned)k << 17);
        }
        wbase += tot;
    }
    if (lane == 0) qcount[wv] = (wbase > WQ) ? WQ : wbase;
    __syncthreads();

    // ---- Phase B: dense drain of both wave queues
    const int q0 = qcount[0];
    const int nq = q0 + qcount[1];
    const float inv_half = 1.0f / 64.0f;
    for (int j = t; j < nq; j += 128) {
        const unsigned item = (j < q0) ? queue[j] : queue[WQ + (j - q0)];
        const int p  = (int)(item & 0x1FFFFu);
        const int g0 = X0 + (int)((item >> 17) & 3u);
        const int b1 = X1 - 2 + (int)((item >> 19) & 15u);
        const int b2 = X2 - 2 + (int)((item >> 23) & 31u);

        const float4 r0 = rec[3 * p + 0];  // c0,c1,c2,density
        const float4 r1 = rec[3 * p + 1];  // A00,A11,A22,A01
        const float4 r2 = rec[3 * p + 2];  // A02,A12,-,-

        const int lo1 = max(b1 - 2, X1), hi1 = min(b1 + 2, X1 + T1 - 1);
        const int lo2 = max(b2 - 2, X2), hi2 = min(b2 + 2, X2 + T2 - 1);

        const float d0 = ((float)g0 - r0.x) * inv_half;
        const float K0 = r1.x * d0 * d0;        // A00 d0^2
        const float u1 = 2.0f * r1.w * d0;      // 2 A01 d0
        const float u2 = 2.0f * r2.x * d0;      // 2 A02 d0
        const int base0 = (g0 - X0) * T1;

        for (int g1 = lo1; g1 <= hi1; ++g1) {
            const float d1 = ((float)g1 - r0.y) * inv_half;
            const float K1 = K0 + d1 * (r1.y * d1 + u1);    // + A11 d1^2 + 2A01 d0 d1
            const float u3 = u2 + 2.0f * r2.y * d1;         // 2A02 d0 + 2A12 d1
            const int base1 = (base0 + (g1 - X1)) * T2;
            for (int g2 = lo2; g2 <= hi2; ++g2) {
                const float d2 = ((float)g2 - r0.z) * inv_half;
                const float mah = K1 + d2 * (r1.z * d2 + u3);
                if (mah <= 9.0f) {
                    atomicAdd(&tile[base1 + (g2 - X2)],
                              __expf(-0.5f * mah) * r0.w);
                }
            }
        }
    }
    __syncthreads();

    // store: 512 f32 = 128 float4, one per thread; rows of 16 f32 = 64 B
    const float4* tl4 = (const float4*)tile;
    const int row = t >> 2;        // 0..31 : (l0,l1)
    const int ch  = t & 3;         // float4 chunk within 16-f32 row
    const int l0 = row >> 3;
    const int l1 = row & 7;
    const int g = ((X0 + l0) * VOX + (X1 + l1)) * VOX + X2 + ch * 4;
    ((float4*)volume)[g >> 2] = tl4[t];
}

extern "C" void kernel_launch(void* const* d_in, const int* in_sizes, int n_in,
                              void* d_out, int out_size, void* d_ws, size_t ws_size,
                              hipStream_t stream) {
    const float* positions = (const float*)d_in[0];
    const float* scales    = (const float*)d_in[1];
    const float* rotations = (const float*)d_in[2];
    const float* density   = (const float*)d_in[3];
    float* volume = (float*)d_out;

    const int n = in_sizes[0] / 3;

    unsigned int* counts = (unsigned int*)d_ws;
    unsigned int* bins   = (unsigned int*)((char*)d_ws + (64 << 10));
    float4* rec          = (float4*)((char*)d_ws + (4 << 20));

    hipMemsetAsync(counts, 0, NCELL * sizeof(unsigned int), stream);

    bin_points<<<(n + 255) / 256, 256, 0, stream>>>(
        positions, scales, rotations, density, counts, bins, rec, n);

    dim3 grid(NT2, NT1, NT0);  // (8, 16, 32) = 4096 blocks of 128 threads
    splat_tiles<<<grid, 128, 0, stream>>>(counts, bins, rec, volume);
    // no volume memset: every voxel is stored exactly once by splat_tiles
}